// Round 9
// baseline (461.262 us; speedup 1.0000x reference)
//
#include <hip/hip_runtime.h>
#include <math.h>

#define B    32
#define S    2048
#define NP   8
#define NCH  8      // attn chunks per batch
#define SCHUNK 256
#define HG   64     // hid-groups of 8
#define BGP  4      // batch groups of 8

__device__ __forceinline__ float sigmoidf_(float x) {
  return 1.0f / (1.0f + __expf(-x));
}

// ---- init W: Wt4[k][hid] = {W_i,W_f,W_g,W_o}[hid-row][k], k concat over [W_ih|W_hh] ----
// grid 128 = 8 hid-tiles x 16 k-tiles, 256 threads
__global__ __launch_bounds__(256)
void k_initW(const float* __restrict__ W_ih, const float* __restrict__ W_hh,
             float4* __restrict__ Wt4) {
  __shared__ float tb[4][64][65];
  const int blk = blockIdx.x, tid = threadIdx.x;
  const int ht = blk & 7, kt = blk >> 3;
  const int h0 = ht * 64, k0 = kt * 64;
  const int r0 = tid >> 6, cc = tid & 63;
  const float* W = (k0 < 512) ? W_ih : W_hh;
  const int kk0 = (k0 < 512) ? k0 : (k0 - 512);
  #pragma unroll
  for (int gi = 0; gi < 4; ++gi)
    for (int rr = r0; rr < 64; rr += 4)
      tb[gi][rr][cc] = W[(size_t)(gi * 512 + h0 + rr) * 512 + kk0 + cc];
  __syncthreads();
  for (int kk = r0; kk < 64; kk += 4)
    Wt4[(size_t)(k0 + kk) * 512 + h0 + cc] =
        make_float4(tb[0][cc][kk], tb[1][cc][kk], tb[2][cc][kk], tb[3][cc][kk]);
}

// ---- init states, fused bias4, num_sent decode. grid 64 x 256 (= B*H threads) ----
__global__ __launch_bounds__(256)
void k_init2(const float* __restrict__ init_h, const float* __restrict__ init_c,
             const float* __restrict__ init_in, const float* __restrict__ b_ih,
             const float* __restrict__ b_hh, const int* __restrict__ ns_raw,
             float* __restrict__ hbuf, float* __restrict__ cbuf,
             float* __restrict__ xin, float4* __restrict__ bias4, int* __restrict__ ns) {
  const int idx = blockIdx.x * 256 + threadIdx.x;
  const int d = idx & 511;
  hbuf[idx] = init_h[d];       // slot 0 = h(-1)
  cbuf[idx] = init_c[d];
  xin[idx]  = init_in[d];
  if (idx < 512) {
    bias4[idx] = make_float4(b_ih[idx]        + b_hh[idx],
                             b_ih[512 + idx]  + b_hh[512 + idx],
                             b_ih[1024 + idx] + b_hh[1024 + idx],
                             b_ih[1536 + idx] + b_hh[1536 + idx]);
  }
  if (idx == 0) {
    // num_sent >= 1 always. If int64 (LE), high word of elem 0 (raw[1]) is 0.
    bool is64 = (ns_raw[1] == 0);
    for (int i = 0; i < B; ++i) ns[i] = is64 ? ns_raw[2 * i] : ns_raw[i];
  }
}

// ---- reduce attn chunk partials -> xin + score -> out[t-1]. grid B x 512 ----
__global__ __launch_bounds__(512)
void k_reduceX(const float* __restrict__ ch_m, const float* __restrict__ ch_l,
               const float* __restrict__ ch_o, const float* __restrict__ scW,
               const float* __restrict__ scb, float* __restrict__ xin,
               float* __restrict__ out, int t) {
  __shared__ float red[512];
  const int b = blockIdx.x, tid = threadIdx.x;
  float M = -1e30f;
  #pragma unroll
  for (int c = 0; c < NCH; ++c) M = fmaxf(M, ch_m[b * NCH + c]);
  float e[NCH]; float L = 0.f;
  #pragma unroll
  for (int c = 0; c < NCH; ++c) {
    e[c] = __expf(ch_m[b * NCH + c] - M);
    L += ch_l[b * NCH + c] * e[c];
  }
  float v = 0.f;
  #pragma unroll
  for (int c = 0; c < NCH; ++c)
    v += ch_o[((size_t)(b * NCH + c)) * 512 + tid] * e[c];
  v *= (1.0f / L);
  if (t < NP) xin[b * 512 + tid] = v;
  red[tid] = v * scW[tid];
  __syncthreads();
  for (int st = 256; st > 0; st >>= 1) {
    if (tid < st) red[tid] += red[tid + st];
    __syncthreads();
  }
  if (tid == 0) out[(t - 1) * B + b] = red[0] + scb[0];
}

// ---- gates + LSTM cell + q-partials ----
// grid 256 = hg(64) x bgp(4), 512 threads = 8 kc-waves.
// lane = bl(8) x ho(8): thread accumulates gates float4 (i,f,g,o) for (hid, b).
// Inner loop: 1 dwordx4 X-load + 4 dwordx4 W-loads per 4k -> 16 FMA. No LDS.
__global__ __launch_bounds__(512)
void k_gates(const float4* __restrict__ Wt4, const float4* __restrict__ bias4,
             const float* __restrict__ xin, const float* __restrict__ Wq,
             float* __restrict__ hbuf, float* __restrict__ cbuf,
             float* __restrict__ qpart, int t) {
  __shared__ float4 gacc[8][64];
  __shared__ float hl[8][8];   // [bl][ho]
  const int tid = threadIdx.x;
  const int hg = blockIdx.x >> 2, bgp = blockIdx.x & 3;
  const int b0 = bgp * 8;
  const int lane = tid & 63, kc = tid >> 6;
  const int ho = lane & 7, bl = lane >> 3;
  const int hid = hg * 8 + ho;
  const float* hprev = hbuf + (t & 1) * (B * 512);
  const float* Xsrc = (kc < 4) ? xin : hprev;
  const int xoff = (b0 + bl) * 512 + (kc & 3) * 128;
  const float4* wp = Wt4 + (size_t)(kc * 128) * 512 + hid;

  float4 acc = make_float4(0.f, 0.f, 0.f, 0.f);
  #pragma unroll 4
  for (int kk = 0; kk < 128; kk += 4) {
    const float4 xv = *(const float4*)&Xsrc[xoff + kk];
    const float4 w0 = wp[(size_t)(kk + 0) * 512];
    const float4 w1 = wp[(size_t)(kk + 1) * 512];
    const float4 w2 = wp[(size_t)(kk + 2) * 512];
    const float4 w3 = wp[(size_t)(kk + 3) * 512];
    acc.x += w0.x * xv.x + w1.x * xv.y + w2.x * xv.z + w3.x * xv.w;
    acc.y += w0.y * xv.x + w1.y * xv.y + w2.y * xv.z + w3.y * xv.w;
    acc.z += w0.z * xv.x + w1.z * xv.y + w2.z * xv.z + w3.z * xv.w;
    acc.w += w0.w * xv.x + w1.w * xv.y + w2.w * xv.z + w3.w * xv.w;
  }
  gacc[kc][lane] = acc;
  __syncthreads();

  if (tid < 64) {
    const int ho2 = tid & 7, bl2 = tid >> 3;
    const int hid2 = hg * 8 + ho2;
    float4 s = gacc[0][tid];
    #pragma unroll
    for (int k2 = 1; k2 < 8; ++k2) {
      float4 g = gacc[k2][tid];
      s.x += g.x; s.y += g.y; s.z += g.z; s.w += g.w;
    }
    const float4 bb = bias4[hid2];
    float i_ = sigmoidf_(s.x + bb.x);
    float f_ = sigmoidf_(s.y + bb.y);
    float g_ = tanhf(s.z + bb.z);
    float o_ = sigmoidf_(s.w + bb.w);
    const int cidx = (b0 + bl2) * 512 + hid2;
    float cn = f_ * cbuf[cidx] + i_ * g_;   // unique owner (hg,bgp) -> safe rw
    cbuf[cidx] = cn;
    float hv = o_ * tanhf(cn);
    hbuf[((t + 1) & 1) * (B * 512) + cidx] = hv;
    hl[bl2][ho2] = hv;
  }
  __syncthreads();

  // q-partials: qpart[hg][b][d] = sum_{ho} h[b][hg*8+ho] * Wq[hg*8+ho][d]
  float wqv[8];
  #pragma unroll
  for (int h2 = 0; h2 < 8; ++h2)
    wqv[h2] = Wq[(size_t)(hg * 8 + h2) * 512 + tid];
  #pragma unroll
  for (int bl2 = 0; bl2 < 8; ++bl2) {
    float a = 0.f;
    #pragma unroll
    for (int h2 = 0; h2 < 8; ++h2) a += hl[bl2][h2] * wqv[h2];
    qpart[((size_t)hg * B + b0 + bl2) * 512 + tid] = a;
  }
}

// ---- attn: q = sum(qpart), one-pass online softmax over chunk ----
// grid 256 = b(32) x ch(8), 512 threads = 8 waves; pairwise rows + 1-pair prefetch.
__global__ __launch_bounds__(512)
void k_attn(const float* __restrict__ enc, const float* __restrict__ qpart,
            const int* __restrict__ ns_buf, float* __restrict__ ch_m,
            float* __restrict__ ch_l, float* __restrict__ ch_o) {
  __shared__ float q_lds[512];
  __shared__ float wm[8], wl[8];
  __shared__ float wo[8][512];
  const int b  = blockIdx.x >> 3;
  const int ch = blockIdx.x & 7;
  const int tid = threadIdx.x;
  const int lane = tid & 63;
  const int wv = tid >> 6;

  {
    float s = 0.f;
    #pragma unroll 8
    for (int hg = 0; hg < HG; ++hg)
      s += qpart[((size_t)hg * B + b) * 512 + tid];
    q_lds[tid] = s;
  }
  __syncthreads();

  const float4 qa  = *(const float4*)&q_lds[lane * 8];
  const float4 qb4 = *(const float4*)&q_lds[lane * 8 + 4];

  const int s0 = ch * SCHUNK;
  const int nsb = ns_buf[b];
  float m = -1e30f, l = 0.f;
  float o0=0,o1=0,o2=0,o3=0,o4=0,o5=0,o6=0,o7=0;

  const int send = min(s0 + SCHUNK, nsb);
  const size_t rowbase = (size_t)b * S;

  int r = s0 + 2 * wv;
  if (r < send) {
    bool has1 = (r + 1 < send);
    const float4* p0 = (const float4*)(enc + (rowbase + r) * 512 + lane * 8);
    const float4* p1 = (const float4*)(enc + (rowbase + (has1 ? r + 1 : r)) * 512 + lane * 8);
    float4 a0 = p0[0], a1 = p0[1];
    float4 c0 = p1[0], c1 = p1[1];
    while (true) {
      const int rn = r + 16;
      const bool hasn = (rn < send);
      float4 na0, na1, nc0, nc1;
      bool nhas1 = false;
      if (hasn) {
        nhas1 = (rn + 1 < send);
        const float4* f0 = (const float4*)(enc + (rowbase + rn) * 512 + lane * 8);
        const float4* f1 = (const float4*)(enc + (rowbase + (nhas1 ? rn + 1 : rn)) * 512 + lane * 8);
        na0 = f0[0]; na1 = f0[1]; nc0 = f1[0]; nc1 = f1[1];
      }
      float d0 = qa.x*a0.x + qa.y*a0.y + qa.z*a0.z + qa.w*a0.w
               + qb4.x*a1.x + qb4.y*a1.y + qb4.z*a1.z + qb4.w*a1.w;
      float d1 = qa.x*c0.x + qa.y*c0.y + qa.z*c0.z + qa.w*c0.w
               + qb4.x*c1.x + qb4.y*c1.y + qb4.z*c1.z + qb4.w*c1.w;
      #pragma unroll
      for (int off = 32; off > 0; off >>= 1) {
        d0 += __shfl_xor(d0, off);
        d1 += __shfl_xor(d1, off);
      }
      if (!has1) d1 = -1e30f;            // wave-uniform
      float nm = fmaxf(m, fmaxf(d0, d1));
      float sc = __expf(m - nm);
      float w0 = __expf(d0 - nm);
      float w1 = __expf(d1 - nm);        // 0 when pair's 2nd row invalid
      l = l * sc + w0 + w1;
      o0 = o0*sc + w0*a0.x + w1*c0.x; o1 = o1*sc + w0*a0.y + w1*c0.y;
      o2 = o2*sc + w0*a0.z + w1*c0.z; o3 = o3*sc + w0*a0.w + w1*c0.w;
      o4 = o4*sc + w0*a1.x + w1*c1.x; o5 = o5*sc + w0*a1.y + w1*c1.y;
      o6 = o6*sc + w0*a1.z + w1*c1.z; o7 = o7*sc + w0*a1.w + w1*c1.w;
      m = nm;
      if (!hasn) break;
      r = rn; has1 = nhas1;
      a0 = na0; a1 = na1; c0 = nc0; c1 = nc1;
    }
  }
  if (lane == 0) { wm[wv] = m; wl[wv] = l; }
  float4* wop = (float4*)&wo[wv][lane * 8];
  wop[0] = make_float4(o0, o1, o2, o3);
  wop[1] = make_float4(o4, o5, o6, o7);
  __syncthreads();

  float M = wm[0];
  #pragma unroll
  for (int w = 1; w < 8; ++w) M = fmaxf(M, wm[w]);
  float e[8]; float L = 0.f;
  #pragma unroll
  for (int w = 0; w < 8; ++w) { e[w] = __expf(wm[w] - M); L += wl[w] * e[w]; }
  if (tid == 0) { ch_m[b * NCH + ch] = M; ch_l[b * NCH + ch] = L; }
  float v = 0.f;
  #pragma unroll
  for (int w = 0; w < 8; ++w) v += wo[w][tid] * e[w];
  ch_o[((size_t)(b * NCH + ch)) * 512 + tid] = v;
}

extern "C" void kernel_launch(void* const* d_in, const int* in_sizes, int n_in,
                              void* d_out, int out_size, void* d_ws, size_t ws_size,
                              hipStream_t stream) {
  const float* enc     = (const float*)d_in[0];
  const int*   ns_raw  = (const int*)d_in[1];
  // d_in[2] = num_pred (8)
  const float* init_h  = (const float*)d_in[3];
  const float* init_c  = (const float*)d_in[4];
  const float* init_in = (const float*)d_in[5];
  const float* W_ih    = (const float*)d_in[6];
  const float* W_hh    = (const float*)d_in[7];
  const float* b_ih    = (const float*)d_in[8];
  const float* b_hh    = (const float*)d_in[9];
  const float* Wq      = (const float*)d_in[10];
  const float* score_W = (const float*)d_in[11];
  const float* score_b = (const float*)d_in[12];
  float* out = (float*)d_out;

  float* ws     = (float*)d_ws;
  float4* Wt4   = (float4*)ws;                // 1024*512 float4 = 2097152 floats
  float4* bias4 = (float4*)(ws + 2097152);    // 2048 floats
  float*  hbuf  = ws + 2099200;               // 2*B*512 = 32768 (double-buffered)
  float*  cbuf  = ws + 2131968;               // 16384
  float*  xin   = ws + 2148352;               // 16384
  float*  qpart = ws + 2164736;               // HG*B*512 = 1048576
  float*  ch_m  = ws + 3213312;               // 256
  float*  ch_l  = ws + 3213568;               // 256
  float*  ch_o  = ws + 3213824;               // B*NCH*512 = 131072
  int*    ns    = (int*)(ws + 3344896);       // 32 ints

  k_initW<<<128, 256, 0, stream>>>(W_ih, W_hh, Wt4);
  k_init2<<<64, 256, 0, stream>>>(init_h, init_c, init_in, b_ih, b_hh, ns_raw,
                                  hbuf, cbuf, xin, bias4, ns);
  for (int t = 0; t < NP; ++t) {
    if (t > 0)
      k_reduceX<<<B, 512, 0, stream>>>(ch_m, ch_l, ch_o, score_W, score_b, xin, out, t);
    k_gates<<<HG * BGP, 512, 0, stream>>>(Wt4, bias4, xin, Wq, hbuf, cbuf, qpart, t);
    k_attn<<<B * NCH, 512, 0, stream>>>(enc, qpart, ns, ch_m, ch_l, ch_o);
  }
  k_reduceX<<<B, 512, 0, stream>>>(ch_m, ch_l, ch_o, score_W, score_b, xin, out, NP);
}

// Round 10
// 365.839 us; speedup vs baseline: 1.2608x; 1.2608x over previous
//
#include <hip/hip_runtime.h>
#include <math.h>

#define B    32
#define S    2048
#define D    512
#define H    512
#define NP   8
#define NSL  32     // hid-slices per step kernel
#define HSL  16     // hid per slice
#define NBT  4      // batch groups
#define BG   8      // batches per group
#define NCH  16     // attn chunks per batch
#define SCHUNK 128

__device__ __forceinline__ float sigmoidf_(float x) {
  return 1.0f / (1.0f + __expf(-x));
}

// ---------------- init: Wt = [W_ih | W_hh]^T (Wt[k][j]), states, num_sent ----------------
__global__ __launch_bounds__(256)
void k_init(const float* __restrict__ W_ih, const float* __restrict__ W_hh,
            const float* __restrict__ init_h, const float* __restrict__ init_c,
            const float* __restrict__ init_in, const int* __restrict__ ns_raw,
            float* __restrict__ Wt, float* __restrict__ hbuf, float* __restrict__ cbuf,
            float* __restrict__ xin0, int* __restrict__ ns) {
  __shared__ float tbuf[64][65];
  const int blk = blockIdx.x, tid = threadIdx.x;
  const int jt = blk & 31, kt = blk >> 5;        // 32 j-tiles x 16 k-tiles of 64x64
  const int j0 = jt * 64, k0 = kt * 64;
  const int r0 = tid >> 6, cc = tid & 63;
  for (int rr = r0; rr < 64; rr += 4) {
    int j = j0 + rr, k = k0 + cc;
    tbuf[rr][cc] = (k < 512) ? W_ih[(size_t)j * 512 + k]
                             : W_hh[(size_t)j * 512 + (k - 512)];
  }
  __syncthreads();
  for (int rr = r0; rr < 64; rr += 4)
    Wt[(size_t)(k0 + rr) * 2048 + j0 + cc] = tbuf[cc][rr];

  int idx = blk * 256 + tid;
  if (idx < B * H) {
    int d = idx & 511;
    hbuf[idx] = init_h[d];   // buffer 0
    cbuf[idx] = init_c[d];
    xin0[idx] = init_in[d];
  }
  if (idx == 0) {
    // num_sent >= 1 always. If int64 (LE), high word of elem 0 (raw[1]) is 0.
    bool is64 = (ns_raw[1] == 0);
    for (int i = 0; i < B; ++i) ns[i] = is64 ? ns_raw[2 * i] : ns_raw[i];
  }
}

// ---------------- fused step kernel (identical to round 7 except NCH=16) ----------------
// grid 128 = (sl: 32 hid-slices) x (bg: 4 groups of 8 batches), 512 threads.
__global__ __launch_bounds__(512, 1)
void k_step(const float* __restrict__ xin0, const float* __restrict__ bih,
            const float* __restrict__ bhh, const float* __restrict__ Wq,
            const float* __restrict__ scW, const float* __restrict__ scb,
            const float* __restrict__ Wt,
            const float* __restrict__ ch_m, const float* __restrict__ ch_l,
            const float* __restrict__ ch_o,
            float* __restrict__ hbuf, float* __restrict__ cbuf,
            float* __restrict__ qpart, float* __restrict__ out, int t) {
  __shared__ float X[BG][1024];       // 32 KB: [xin | h(t-1)] per batch
  __shared__ float gacc[8][64][9];    // 18 KB (pad 9 -> 2-way banks)
  __shared__ float gl[4][16][8];      // gate values
  __shared__ float hl[8][16];         // h slice for qpart
  __shared__ float sred[8][8];        // score partials [wave][b]

  const int tid = threadIdx.x;
  const int sl = blockIdx.x >> 2;     // 0..31
  const int bg = blockIdx.x & 3;      // 0..3
  const int b0 = bg * BG;

  // ---- phase A ----
  if (t == 0) {
    #pragma unroll
    for (int bl = 0; bl < BG; ++bl)
      X[bl][tid] = xin0[(b0 + bl) * 512 + tid];
  } else {
    const float swd = scW[tid];
    #pragma unroll
    for (int bl = 0; bl < BG; ++bl) {
      const int b = b0 + bl;
      float M = -1e30f;
      #pragma unroll
      for (int c = 0; c < NCH; ++c) M = fmaxf(M, ch_m[b * NCH + c]);
      float e[NCH]; float L = 0.f;
      #pragma unroll
      for (int c = 0; c < NCH; ++c) {
        e[c] = __expf(ch_m[b * NCH + c] - M);
        L += ch_l[b * NCH + c] * e[c];
      }
      float v = 0.f;
      #pragma unroll
      for (int c = 0; c < NCH; ++c)
        v += ch_o[((size_t)(b * NCH + c)) * 512 + tid] * e[c];
      v *= (1.0f / L);
      X[bl][tid] = v;
      float p = v * swd;
      #pragma unroll
      for (int off = 32; off > 0; off >>= 1) p += __shfl_xor(p, off);
      if ((tid & 63) == 0) sred[tid >> 6][bl] = p;
    }
  }
  // copy h(t-1) into X[.][512..1023]
  if (t < NP) {
    const float4* hsrc = (const float4*)(hbuf + (t & 1) * (B * 512));
    #pragma unroll
    for (int it = 0; it < 2; ++it) {
      int idx = it * 512 + tid;      // 0..1023
      int bl = idx >> 7;
      int off = idx & 127;
      float4 hv = hsrc[(b0 + bl) * 128 + off];
      *(float4*)&X[bl][512 + off * 4] = hv;
    }
  }
  __syncthreads();

  if (t >= 1 && tid < BG) {
    float s = 0.f;
    #pragma unroll
    for (int w = 0; w < 8; ++w) s += sred[w][tid];
    if (sl == 0) out[(t - 1) * B + b0 + tid] = s + scb[0];
  }
  if (t >= NP) return;   // t==8: final-score-only call

  // ---- phase B: gates ----
  {
    const int jloc = tid & 63;              // (gi, ho)
    const int kc = tid >> 6;                // wave id = k-chunk
    const int gi = jloc >> 4, ho = jloc & 15;
    const int jg = gi * 512 + sl * HSL + ho;
    const int k0c = kc * 128;
    const float* wp = Wt + (size_t)k0c * 2048 + jg;
    float acc[BG] = {0, 0, 0, 0, 0, 0, 0, 0};
    for (int kk = 0; kk < 32; ++kk) {
      float wv0 = wp[(size_t)(kk * 4 + 0) * 2048];
      float wv1 = wp[(size_t)(kk * 4 + 1) * 2048];
      float wv2 = wp[(size_t)(kk * 4 + 2) * 2048];
      float wv3 = wp[(size_t)(kk * 4 + 3) * 2048];
      #pragma unroll
      for (int bl = 0; bl < BG; ++bl) {
        const float4 xv = *(const float4*)&X[bl][k0c + kk * 4];  // LDS broadcast
        acc[bl] += wv0 * xv.x + wv1 * xv.y + wv2 * xv.z + wv3 * xv.w;
      }
    }
    #pragma unroll
    for (int bl = 0; bl < BG; ++bl) gacc[kc][jloc][bl] = acc[bl];
  }
  __syncthreads();

  // ---- kc-reduce + bias -> gl ----
  {
    const int bl = tid >> 6, jloc = tid & 63;
    const int gi = jloc >> 4, ho = jloc & 15;
    const int jg = gi * 512 + sl * HSL + ho;
    float g = bih[jg] + bhh[jg];
    #pragma unroll
    for (int kc = 0; kc < 8; ++kc) g += gacc[kc][jloc][bl];
    gl[gi][ho][bl] = g;
  }
  __syncthreads();

  // ---- LSTM cell ----
  if (tid < 128) {
    const int ho = tid & 15, bl = tid >> 4;
    const int bglob = b0 + bl, hid = sl * HSL + ho;
    float i_ = sigmoidf_(gl[0][ho][bl]);
    float f_ = sigmoidf_(gl[1][ho][bl]);
    float g_ = tanhf(gl[2][ho][bl]);
    float o_ = sigmoidf_(gl[3][ho][bl]);
    float cv = cbuf[bglob * 512 + hid];          // unique owner (sl,bg)
    float cn = f_ * cv + i_ * g_;
    cbuf[bglob * 512 + hid] = cn;
    float hv = o_ * tanhf(cn);
    hbuf[((t + 1) & 1) * (B * 512) + bglob * 512 + hid] = hv;
    hl[bl][ho] = hv;
  }
  __syncthreads();

  // ---- q-partials: qpart[sl][b][d] = sum_{ho} h[b][sl*16+ho] * Wq[sl*16+ho][d] ----
  {
    float w[HSL];
    #pragma unroll
    for (int ho = 0; ho < HSL; ++ho)
      w[ho] = Wq[(size_t)(sl * HSL + ho) * 512 + tid];
    #pragma unroll
    for (int bl = 0; bl < BG; ++bl) {
      float acc = 0.f;
      #pragma unroll
      for (int ho = 0; ho < HSL; ++ho) acc += hl[bl][ho] * w[ho];
      qpart[((size_t)sl * B + b0 + bl) * 512 + tid] = acc;
    }
  }
}

// ---------------- attn: q = sum(qpart), depth-2 pipelined online softmax ----------------
// grid 512 = (b: 32) x (ch: 16), 512 threads = 8 waves (2 blocks/CU).
// Wave wv handles pairs r = s0 + 2*wv + 16*i; 2 pairs (8 KB) in flight ahead of compute.
__global__ __launch_bounds__(512, 2)
void k_attn(const float* __restrict__ enc, const float* __restrict__ qpart,
            const int* __restrict__ ns_buf, float* __restrict__ ch_m,
            float* __restrict__ ch_l, float* __restrict__ ch_o) {
  __shared__ float q_lds[512];
  __shared__ float wm[8], wl[8];
  __shared__ float wo[8][512];
  const int b  = blockIdx.x >> 4;
  const int ch = blockIdx.x & 15;
  const int tid = threadIdx.x;
  const int lane = tid & 63;
  const int wv = tid >> 6;

  // q = sum over 32 slices
  {
    float s = 0.f;
    #pragma unroll 8
    for (int sl = 0; sl < NSL; ++sl)
      s += qpart[((size_t)sl * B + b) * 512 + tid];
    q_lds[tid] = s;
  }
  __syncthreads();

  const float4 qa  = *(const float4*)&q_lds[lane * 8];
  const float4 qb4 = *(const float4*)&q_lds[lane * 8 + 4];

  const int s0 = ch * SCHUNK;
  const int nsb = ns_buf[b];
  const int send = min(s0 + SCHUNK, nsb);
  const size_t rowbase = (size_t)b * S;
  const int first = s0 + 2 * wv;
  const int npair = (first < send) ? ((send - first + 15) >> 4) : 0;  // <= 8

  float m = -1e30f, l = 0.f;
  float o0=0,o1=0,o2=0,o3=0,o4=0,o5=0,o6=0,o7=0;

  float4 A0, A1, A2, A3, B0, B1, B2, B3;
  bool av = false, bv = false;

#define LOADP(i, x0, x1, x2, x3, v)                                          \
  {                                                                          \
    const int r_ = first + 16 * (i);                                         \
    (v) = (r_ + 1 < send);                                                   \
    const float4* p0_ = (const float4*)(enc + (rowbase + r_) * 512 + lane * 8); \
    const float4* p1_ = (const float4*)(enc + (rowbase + ((v) ? r_ + 1 : r_)) * 512 + lane * 8); \
    (x0) = p0_[0]; (x1) = p0_[1]; (x2) = p1_[0]; (x3) = p1_[1];              \
  }

  if (npair > 0) LOADP(0, A0, A1, A2, A3, av);
  if (npair > 1) LOADP(1, B0, B1, B2, B3, bv);

  for (int i = 0; i < npair; ++i) {
    float4 C0 = A0, C1 = A1, C2 = A2, C3 = A3;
    bool cv = false;
    if (i + 2 < npair) LOADP(i + 2, C0, C1, C2, C3, cv);

    float d0 = qa.x*A0.x + qa.y*A0.y + qa.z*A0.z + qa.w*A0.w
             + qb4.x*A1.x + qb4.y*A1.y + qb4.z*A1.z + qb4.w*A1.w;
    float d1 = qa.x*A2.x + qa.y*A2.y + qa.z*A2.z + qa.w*A2.w
             + qb4.x*A3.x + qb4.y*A3.y + qb4.z*A3.z + qb4.w*A3.w;
    #pragma unroll
    for (int off = 32; off > 0; off >>= 1) {
      d0 += __shfl_xor(d0, off);
      d1 += __shfl_xor(d1, off);
    }
    if (!av) d1 = -1e30f;            // wave-uniform
    float nm = fmaxf(m, fmaxf(d0, d1));
    float sc = __expf(m - nm);
    float w0 = __expf(d0 - nm);
    float w1 = __expf(d1 - nm);      // 0 when pair's 2nd row invalid
    l = l * sc + w0 + w1;
    o0 = o0*sc + w0*A0.x + w1*A2.x; o1 = o1*sc + w0*A0.y + w1*A2.y;
    o2 = o2*sc + w0*A0.z + w1*A2.z; o3 = o3*sc + w0*A0.w + w1*A2.w;
    o4 = o4*sc + w0*A1.x + w1*A3.x; o5 = o5*sc + w0*A1.y + w1*A3.y;
    o6 = o6*sc + w0*A1.z + w1*A3.z; o7 = o7*sc + w0*A1.w + w1*A3.w;
    m = nm;

    A0 = B0; A1 = B1; A2 = B2; A3 = B3; av = bv;
    B0 = C0; B1 = C1; B2 = C2; B3 = C3; bv = cv;
  }
#undef LOADP

  if (lane == 0) { wm[wv] = m; wl[wv] = l; }
  float4* wop = (float4*)&wo[wv][lane * 8];
  wop[0] = make_float4(o0, o1, o2, o3);
  wop[1] = make_float4(o4, o5, o6, o7);
  __syncthreads();

  float M = wm[0];
  #pragma unroll
  for (int w = 1; w < 8; ++w) M = fmaxf(M, wm[w]);
  float e[8]; float L = 0.f;
  #pragma unroll
  for (int w = 0; w < 8; ++w) { e[w] = __expf(wm[w] - M); L += wl[w] * e[w]; }
  if (tid == 0) { ch_m[b * NCH + ch] = M; ch_l[b * NCH + ch] = L; }
  float v = 0.f;
  #pragma unroll
  for (int w = 0; w < 8; ++w) v += wo[w][tid] * e[w];
  ch_o[((size_t)(b * NCH + ch)) * 512 + tid] = v;
}

extern "C" void kernel_launch(void* const* d_in, const int* in_sizes, int n_in,
                              void* d_out, int out_size, void* d_ws, size_t ws_size,
                              hipStream_t stream) {
  const float* enc     = (const float*)d_in[0];
  const int*   ns_raw  = (const int*)d_in[1];
  // d_in[2] = num_pred (8)
  const float* init_h  = (const float*)d_in[3];
  const float* init_c  = (const float*)d_in[4];
  const float* init_in = (const float*)d_in[5];
  const float* W_ih    = (const float*)d_in[6];
  const float* W_hh    = (const float*)d_in[7];
  const float* b_ih    = (const float*)d_in[8];
  const float* b_hh    = (const float*)d_in[9];
  const float* Wq      = (const float*)d_in[10];
  const float* score_W = (const float*)d_in[11];
  const float* score_b = (const float*)d_in[12];
  float* out = (float*)d_out;

  float* ws    = (float*)d_ws;
  float* Wt    = ws;                  // 1024*2048 = 2097152
  float* hbuf  = ws + 2097152;        // 2*B*H = 32768 (double-buffered)
  float* cbuf  = ws + 2129920;        // 16384
  float* xin0  = ws + 2146304;        // 16384
  float* qpart = ws + 2162688;        // NSL*B*512 = 524288
  float* ch_m  = ws + 2686976;        // B*NCH = 512
  float* ch_l  = ws + 2687488;        // 512
  float* ch_o  = ws + 2688000;        // B*NCH*512 = 262144
  int*   ns    = (int*)(ws + 2950144);  // 32 ints

  k_init<<<512, 256, 0, stream>>>(W_ih, W_hh, init_h, init_c, init_in, ns_raw,
                                  Wt, hbuf, cbuf, xin0, ns);
  for (int t = 0; t < NP; ++t) {
    k_step<<<NSL * NBT, 512, 0, stream>>>(xin0, b_ih, b_hh, Wq, score_W, score_b, Wt,
                                          ch_m, ch_l, ch_o, hbuf, cbuf, qpart, out, t);
    k_attn<<<B * NCH, 512, 0, stream>>>(enc, qpart, ns, ch_m, ch_l, ch_o);
  }
  k_step<<<NSL * NBT, 512, 0, stream>>>(xin0, b_ih, b_hh, Wq, score_W, score_b, Wt,
                                        ch_m, ch_l, ch_o, hbuf, cbuf, qpart, out, NP);
}

// Round 11
// 309.611 us; speedup vs baseline: 1.4898x; 1.1816x over previous
//
#include <hip/hip_runtime.h>
#include <math.h>

#define B    32
#define S    2048
#define D    512
#define H    512
#define NP   8
#define NSL  32     // hid-slices per step kernel
#define HSL  16     // hid per slice
#define NBT  8      // batch groups
#define BG   4      // batches per group
#define NCH  8      // attn chunks per batch
#define SCHUNK 256

__device__ __forceinline__ float sigmoidf_(float x) {
  return 1.0f / (1.0f + __expf(-x));
}

// ---------------- init: Wt = [W_ih | W_hh]^T (Wt[k][j]), states, num_sent ----------------
__global__ __launch_bounds__(256)
void k_init(const float* __restrict__ W_ih, const float* __restrict__ W_hh,
            const float* __restrict__ init_h, const float* __restrict__ init_c,
            const float* __restrict__ init_in, const int* __restrict__ ns_raw,
            float* __restrict__ Wt, float* __restrict__ hbuf, float* __restrict__ cbuf,
            float* __restrict__ xin0, int* __restrict__ ns) {
  __shared__ float tbuf[64][65];
  const int blk = blockIdx.x, tid = threadIdx.x;
  const int jt = blk & 31, kt = blk >> 5;        // 32 j-tiles x 16 k-tiles of 64x64
  const int j0 = jt * 64, k0 = kt * 64;
  const int r0 = tid >> 6, cc = tid & 63;
  for (int rr = r0; rr < 64; rr += 4) {
    int j = j0 + rr, k = k0 + cc;
    tbuf[rr][cc] = (k < 512) ? W_ih[(size_t)j * 512 + k]
                             : W_hh[(size_t)j * 512 + (k - 512)];
  }
  __syncthreads();
  for (int rr = r0; rr < 64; rr += 4)
    Wt[(size_t)(k0 + rr) * 2048 + j0 + cc] = tbuf[cc][rr];

  int idx = blk * 256 + tid;
  if (idx < B * H) {
    int d = idx & 511;
    hbuf[idx] = init_h[d];   // buffer 0
    cbuf[idx] = init_c[d];
    xin0[idx] = init_in[d];
  }
  if (idx == 0) {
    // num_sent >= 1 always. If int64 (LE), high word of elem 0 (raw[1]) is 0.
    bool is64 = (ns_raw[1] == 0);
    for (int i = 0; i < B; ++i) ns[i] = is64 ? ns_raw[2 * i] : ns_raw[i];
  }
}

// ---------------- fused step kernel ----------------
// grid 256 = (sl: 32 hid-slices) x (bg: 8 groups of 4 batches), 512 threads.
// Phase A: reduce(t-1): combine attn chunk partials -> X (LDS) + score -> out[t-1]
// Phase B: gates, kc-split over 8 waves: per 4k = 4 w-loads + 4 X b128 + 16 FMA
// Phase C: LSTM cell -> h(t), c; q-partials qpart[sl][b][d]
// t==8: phase A only (final score).
__global__ __launch_bounds__(512, 1)
void k_step(const float* __restrict__ xin0, const float* __restrict__ bih,
            const float* __restrict__ bhh, const float* __restrict__ Wq,
            const float* __restrict__ scW, const float* __restrict__ scb,
            const float* __restrict__ Wt,
            const float* __restrict__ ch_m, const float* __restrict__ ch_l,
            const float* __restrict__ ch_o,
            float* __restrict__ hbuf, float* __restrict__ cbuf,
            float* __restrict__ qpart, float* __restrict__ out, int t) {
  __shared__ float X[BG][1024];       // 16 KB: [xin | h(t-1)] per batch
  __shared__ float gacc[8][64][5];    // 10 KB (pad 5)
  __shared__ float gl[4][16][BG];     // gate values
  __shared__ float hl[BG][16];        // h slice for qpart
  __shared__ float sred[8][BG];       // score partials [wave][b]

  const int tid = threadIdx.x;
  const int sl = blockIdx.x >> 3;     // 0..31
  const int bg = blockIdx.x & 7;      // 0..7
  const int b0 = bg * BG;

  // ---- phase A ----
  if (t == 0) {
    #pragma unroll
    for (int bl = 0; bl < BG; ++bl)
      X[bl][tid] = xin0[(b0 + bl) * 512 + tid];
  } else {
    const float swd = scW[tid];
    #pragma unroll
    for (int bl = 0; bl < BG; ++bl) {
      const int b = b0 + bl;
      float M = -1e30f;
      #pragma unroll
      for (int c = 0; c < NCH; ++c) M = fmaxf(M, ch_m[b * NCH + c]);
      float e[NCH]; float L = 0.f;
      #pragma unroll
      for (int c = 0; c < NCH; ++c) {
        e[c] = __expf(ch_m[b * NCH + c] - M);
        L += ch_l[b * NCH + c] * e[c];
      }
      float v = 0.f;
      #pragma unroll
      for (int c = 0; c < NCH; ++c)
        v += ch_o[((size_t)(b * NCH + c)) * 512 + tid] * e[c];
      v *= (1.0f / L);
      X[bl][tid] = v;
      float p = v * swd;
      #pragma unroll
      for (int off = 32; off > 0; off >>= 1) p += __shfl_xor(p, off);
      if ((tid & 63) == 0) sred[tid >> 6][bl] = p;
    }
  }
  // copy h(t-1) into X[.][512..1023]: 4 batches x 128 float4 = 512 float4
  if (t < NP) {
    const float4* hsrc = (const float4*)(hbuf + (t & 1) * (B * 512));
    int bl = tid >> 7;
    int off = tid & 127;
    float4 hv = hsrc[(b0 + bl) * 128 + off];
    *(float4*)&X[bl][512 + off * 4] = hv;
  }
  __syncthreads();

  if (t >= 1 && tid < BG) {
    float s = 0.f;
    #pragma unroll
    for (int w = 0; w < 8; ++w) s += sred[w][tid];
    if (sl == 0) out[(t - 1) * B + b0 + tid] = s + scb[0];
  }
  if (t >= NP) return;   // t==8: final-score-only call

  // ---- phase B: gates ----
  {
    const int jloc = tid & 63;              // (gi, ho)
    const int kc = tid >> 6;                // wave id = k-chunk
    const int gi = jloc >> 4, ho = jloc & 15;
    const int jg = gi * 512 + sl * HSL + ho;
    const int k0c = kc * 128;
    const float* wp = Wt + (size_t)k0c * 2048 + jg;
    float acc[BG] = {0, 0, 0, 0};
    for (int kk = 0; kk < 32; ++kk) {
      float wv0 = wp[(size_t)(kk * 4 + 0) * 2048];
      float wv1 = wp[(size_t)(kk * 4 + 1) * 2048];
      float wv2 = wp[(size_t)(kk * 4 + 2) * 2048];
      float wv3 = wp[(size_t)(kk * 4 + 3) * 2048];
      #pragma unroll
      for (int bl = 0; bl < BG; ++bl) {
        const float4 xv = *(const float4*)&X[bl][k0c + kk * 4];  // LDS broadcast
        acc[bl] += wv0 * xv.x + wv1 * xv.y + wv2 * xv.z + wv3 * xv.w;
      }
    }
    #pragma unroll
    for (int bl = 0; bl < BG; ++bl) gacc[kc][jloc][bl] = acc[bl];
  }
  __syncthreads();

  // ---- kc-reduce + bias -> gl (256 threads: 4 bl x 64 jloc) ----
  if (tid < 256) {
    const int bl = tid >> 6, jloc = tid & 63;
    const int gi = jloc >> 4, ho = jloc & 15;
    const int jg = gi * 512 + sl * HSL + ho;
    float g = bih[jg] + bhh[jg];
    #pragma unroll
    for (int kc = 0; kc < 8; ++kc) g += gacc[kc][jloc][bl];
    gl[gi][ho][bl] = g;
  }
  __syncthreads();

  // ---- LSTM cell (64 threads: 4 bl x 16 ho) ----
  if (tid < BG * HSL) {
    const int ho = tid & 15, bl = tid >> 4;
    const int bglob = b0 + bl, hid = sl * HSL + ho;
    float i_ = sigmoidf_(gl[0][ho][bl]);
    float f_ = sigmoidf_(gl[1][ho][bl]);
    float g_ = tanhf(gl[2][ho][bl]);
    float o_ = sigmoidf_(gl[3][ho][bl]);
    float cv = cbuf[bglob * 512 + hid];          // unique owner (sl,bg)
    float cn = f_ * cv + i_ * g_;
    cbuf[bglob * 512 + hid] = cn;
    float hv = o_ * tanhf(cn);
    hbuf[((t + 1) & 1) * (B * 512) + bglob * 512 + hid] = hv;
    hl[bl][ho] = hv;
  }
  __syncthreads();

  // ---- q-partials: qpart[sl][b][d] = sum_{ho} h[b][sl*16+ho] * Wq[sl*16+ho][d] ----
  {
    float w[HSL];
    #pragma unroll
    for (int ho = 0; ho < HSL; ++ho)
      w[ho] = Wq[(size_t)(sl * HSL + ho) * 512 + tid];
    #pragma unroll
    for (int bl = 0; bl < BG; ++bl) {
      float acc = 0.f;
      #pragma unroll
      for (int ho = 0; ho < HSL; ++ho) acc += hl[bl][ho] * w[ho];
      qpart[((size_t)sl * B + b0 + bl) * 512 + tid] = acc;
    }
  }
}

// ---------------- attn: q = sum(qpart), one-pass online softmax over chunk ----------------
// grid 256 = (b: 32) x (ch: 8), 512 threads = 8 waves; pairwise rows + 1-pair prefetch.
__global__ __launch_bounds__(512, 1)
void k_attn(const float* __restrict__ enc, const float* __restrict__ qpart,
            const int* __restrict__ ns_buf, float* __restrict__ ch_m,
            float* __restrict__ ch_l, float* __restrict__ ch_o) {
  __shared__ float q_lds[512];
  __shared__ float wm[8], wl[8];
  __shared__ float wo[8][512];
  const int b  = blockIdx.x >> 3;
  const int ch = blockIdx.x & 7;
  const int tid = threadIdx.x;
  const int lane = tid & 63;
  const int wv = tid >> 6;

  // q = sum over 32 slices
  {
    float s = 0.f;
    #pragma unroll 8
    for (int sl = 0; sl < NSL; ++sl)
      s += qpart[((size_t)sl * B + b) * 512 + tid];
    q_lds[tid] = s;
  }
  __syncthreads();

  const float4 qa  = *(const float4*)&q_lds[lane * 8];
  const float4 qb4 = *(const float4*)&q_lds[lane * 8 + 4];

  const int s0 = ch * SCHUNK;
  const int nsb = ns_buf[b];
  float m = -1e30f, l = 0.f;
  float o0=0,o1=0,o2=0,o3=0,o4=0,o5=0,o6=0,o7=0;

  const int send = min(s0 + SCHUNK, nsb);
  const size_t rowbase = (size_t)b * S;

  int r = s0 + 2 * wv;
  if (r < send) {
    bool has1 = (r + 1 < send);
    const float4* p0 = (const float4*)(enc + (rowbase + r) * 512 + lane * 8);
    const float4* p1 = (const float4*)(enc + (rowbase + (has1 ? r + 1 : r)) * 512 + lane * 8);
    float4 a0 = p0[0], a1 = p0[1];
    float4 c0 = p1[0], c1 = p1[1];
    while (true) {
      const int rn = r + 16;
      const bool hasn = (rn < send);
      float4 na0, na1, nc0, nc1;
      bool nhas1 = false;
      if (hasn) {
        nhas1 = (rn + 1 < send);
        const float4* f0 = (const float4*)(enc + (rowbase + rn) * 512 + lane * 8);
        const float4* f1 = (const float4*)(enc + (rowbase + (nhas1 ? rn + 1 : rn)) * 512 + lane * 8);
        na0 = f0[0]; na1 = f0[1]; nc0 = f1[0]; nc1 = f1[1];
      }
      float d0 = qa.x*a0.x + qa.y*a0.y + qa.z*a0.z + qa.w*a0.w
               + qb4.x*a1.x + qb4.y*a1.y + qb4.z*a1.z + qb4.w*a1.w;
      float d1 = qa.x*c0.x + qa.y*c0.y + qa.z*c0.z + qa.w*c0.w
               + qb4.x*c1.x + qb4.y*c1.y + qb4.z*c1.z + qb4.w*c1.w;
      #pragma unroll
      for (int off = 32; off > 0; off >>= 1) {
        d0 += __shfl_xor(d0, off);
        d1 += __shfl_xor(d1, off);
      }
      if (!has1) d1 = -1e30f;            // wave-uniform
      float nm = fmaxf(m, fmaxf(d0, d1));
      float sc = __expf(m - nm);
      float w0 = __expf(d0 - nm);
      float w1 = __expf(d1 - nm);        // 0 when pair's 2nd row invalid
      l = l * sc + w0 + w1;
      o0 = o0*sc + w0*a0.x + w1*c0.x; o1 = o1*sc + w0*a0.y + w1*c0.y;
      o2 = o2*sc + w0*a0.z + w1*c0.z; o3 = o3*sc + w0*a0.w + w1*c0.w;
      o4 = o4*sc + w0*a1.x + w1*c1.x; o5 = o5*sc + w0*a1.y + w1*c1.y;
      o6 = o6*sc + w0*a1.z + w1*c1.z; o7 = o7*sc + w0*a1.w + w1*c1.w;
      m = nm;
      if (!hasn) break;
      r = rn; has1 = nhas1;
      a0 = na0; a1 = na1; c0 = nc0; c1 = nc1;
    }
  }
  if (lane == 0) { wm[wv] = m; wl[wv] = l; }
  float4* wop = (float4*)&wo[wv][lane * 8];
  wop[0] = make_float4(o0, o1, o2, o3);
  wop[1] = make_float4(o4, o5, o6, o7);
  __syncthreads();

  float M = wm[0];
  #pragma unroll
  for (int w = 1; w < 8; ++w) M = fmaxf(M, wm[w]);
  float e[8]; float L = 0.f;
  #pragma unroll
  for (int w = 0; w < 8; ++w) { e[w] = __expf(wm[w] - M); L += wl[w] * e[w]; }
  if (tid == 0) { ch_m[b * NCH + ch] = M; ch_l[b * NCH + ch] = L; }
  float v = 0.f;
  #pragma unroll
  for (int w = 0; w < 8; ++w) v += wo[w][tid] * e[w];
  ch_o[((size_t)(b * NCH + ch)) * 512 + tid] = v;
}

extern "C" void kernel_launch(void* const* d_in, const int* in_sizes, int n_in,
                              void* d_out, int out_size, void* d_ws, size_t ws_size,
                              hipStream_t stream) {
  const float* enc     = (const float*)d_in[0];
  const int*   ns_raw  = (const int*)d_in[1];
  // d_in[2] = num_pred (8)
  const float* init_h  = (const float*)d_in[3];
  const float* init_c  = (const float*)d_in[4];
  const float* init_in = (const float*)d_in[5];
  const float* W_ih    = (const float*)d_in[6];
  const float* W_hh    = (const float*)d_in[7];
  const float* b_ih    = (const float*)d_in[8];
  const float* b_hh    = (const float*)d_in[9];
  const float* Wq      = (const float*)d_in[10];
  const float* score_W = (const float*)d_in[11];
  const float* score_b = (const float*)d_in[12];
  float* out = (float*)d_out;

  float* ws    = (float*)d_ws;
  float* Wt    = ws;                  // 1024*2048 = 2097152
  float* hbuf  = ws + 2097152;        // 2*B*H = 32768 (double-buffered)
  float* cbuf  = ws + 2129920;        // 16384
  float* xin0  = ws + 2146304;        // 16384
  float* qpart = ws + 2162688;        // NSL*B*512 = 524288
  float* ch_m  = ws + 2686976;        // B*NCH = 256
  float* ch_l  = ws + 2687232;        // 256
  float* ch_o  = ws + 2687488;        // B*NCH*512 = 131072
  int*   ns    = (int*)(ws + 2818560); // 32 ints

  k_init<<<512, 256, 0, stream>>>(W_ih, W_hh, init_h, init_c, init_in, ns_raw,
                                  Wt, hbuf, cbuf, xin0, ns);
  for (int t = 0; t < NP; ++t) {
    k_step<<<NSL * NBT, 512, 0, stream>>>(xin0, b_ih, b_hh, Wq, score_W, score_b, Wt,
                                          ch_m, ch_l, ch_o, hbuf, cbuf, qpart, out, t);
    k_attn<<<B * NCH, 512, 0, stream>>>(enc, qpart, ns, ch_m, ch_l, ch_o);
  }
  k_step<<<NSL * NBT, 512, 0, stream>>>(xin0, b_ih, b_hh, Wq, score_W, score_b, Wt,
                                        ch_m, ch_l, ch_o, hbuf, cbuf, qpart, out, NP);
}